// Round 9
// baseline (340.561 us; speedup 1.0000x reference)
//
#include <hip/hip_runtime.h>
#include <float.h>

#define T_TOTAL 32768
#define KC      8192
#define DIM     256

#define LOSS_IDX  ((size_t)T_TOTAL * DIM)      // 8388608
#define USAGE_IDX (LOSS_IDX + 1)

typedef short s16x8 __attribute__((ext_vector_type(8)));
typedef float f32x4 __attribute__((ext_vector_type(4)));

// ws layout (bytes):
#define WS_W2    0                 // f32[8192]
#define WS_FLAGS 32768             // i32[8192]
#define WS_CNT   65536             // i32[2]: {used_count, blocks_done}
#define WS_CBF   65552             // u16[8192*256] = 4 MB (16B aligned)

__device__ __forceinline__ unsigned short f2bf(float f) {
    unsigned int u = __float_as_uint(f);
    u += 0x7FFFu + ((u >> 16) & 1u);   // RTNE
    return (unsigned short)(u >> 16);
}

// ---------------------------------------------------------------------------
// prep: cb->bf16 + exact fp32 w2; flags zero (blocks 0..31); scalars (block 0)
__global__ __launch_bounds__(256) void vq_prep(const float* __restrict__ cb,
                                               unsigned short* __restrict__ cbb,
                                               float* __restrict__ w2,
                                               int* __restrict__ flags,
                                               int* __restrict__ cnt,
                                               float* __restrict__ out) {
    const int blk = blockIdx.x, tid = threadIdx.x;
    size_t i = (size_t)blk * 2048 + (size_t)tid * 8;
    float4 a = *(const float4*)(cb + i);
    float4 b = *(const float4*)(cb + i + 4);
    uint4 o;
    o.x = (unsigned)f2bf(a.x) | ((unsigned)f2bf(a.y) << 16);
    o.y = (unsigned)f2bf(a.z) | ((unsigned)f2bf(a.w) << 16);
    o.z = (unsigned)f2bf(b.x) | ((unsigned)f2bf(b.y) << 16);
    o.w = (unsigned)f2bf(b.z) | ((unsigned)f2bf(b.w) << 16);
    *(uint4*)(cbb + i) = o;
    float s = a.x * a.x + a.y * a.y + a.z * a.z + a.w * a.w
            + b.x * b.x + b.y * b.y + b.z * b.z + b.w * b.w;
    #pragma unroll
    for (int m = 1; m <= 16; m <<= 1) s += __shfl_xor(s, m);
    if ((tid & 31) == 0) w2[blk * 8 + (tid >> 5)] = s;
    if (blk < 32) flags[blk * 256 + tid] = 0;
    if (blk == 0 && tid == 0) {
        out[LOSS_IDX] = 0.0f; out[USAGE_IDX] = 0.0f;
        cnt[0] = 0; cnt[1] = 0;
    }
}

// ---------------------------------------------------------------------------
// main: block = 128 tokens x all 8192 codes, grid 256 (1 block/CU), 8 waves.
// wave w: wr=w>>2 token half (64 tokens, A in 128 regs), wc=w&3 code quarter.
// Window = 32 codes x 64 k = 4 KB, 256 windows. Wave-private 4-deep LDS
// buffers + register-pipelined fragments (see r8 notes). Usage counting is
// fused: atomicExch on flags + device counter; last-done block writes usage.
__global__ __launch_bounds__(512, 2) void vq_main(const unsigned short* __restrict__ cbb,
                                                  const float* __restrict__ w2g,
                                                  const float* __restrict__ z_e,
                                                  const float* __restrict__ cb,
                                                  float* __restrict__ out,
                                                  int* __restrict__ flags,
                                                  int* __restrict__ cnt) {
    __shared__ unsigned short ca[8][4][2048];   // [wave][buf][4 KB] = 128 KB
    __shared__ unsigned long long smin[128];
    __shared__ float wls[8];

    const int tid  = threadIdx.x;
    const int lane = tid & 63;
    const int w    = tid >> 6;        // 0..7
    const int wr   = w >> 2;          // token half
    const int wc   = w & 3;           // code quarter
    const int quad = lane >> 4;
    const int l15  = lane & 15;
    const int t0   = blockIdx.x * 128;

    if (tid < 128) smin[tid] = ~0ULL;
    __syncthreads();                  // smin published before any wave's epilogue

    const int srow = lane >> 3;       // 0..7
    const int ssl  = lane & 7;        // LDS slot position
    #define STAGE(WIN, BP)                                                              \
        {                                                                               \
            int _c  = (WIN) >> 2;                                                       \
            int _kw = (WIN) & 3;                                                        \
            _Pragma("unroll")                                                           \
            for (int q = 0; q < 4; ++q) {                                               \
                int lr = q * 8 + srow;                                                  \
                int sl = ssl ^ (lr & 7);                                                \
                __builtin_amdgcn_global_load_lds(                                       \
                    (const __attribute__((address_space(1))) void*)                     \
                        (cbb + (size_t)(_c * 128 + wc * 32 + lr) * DIM + _kw * 64 + sl * 8), \
                    (__attribute__((address_space(3))) void*)(&ca[w][BP][q * 512]),     \
                    16, 0, 0);                                                          \
            }                                                                           \
        }

    #define READFRAGS(FB, WIN, BP)                                                     \
        {                                                                               \
            _Pragma("unroll")                                                           \
            for (int kk = 0; kk < 2; ++kk)                                              \
                _Pragma("unroll")                                                       \
                for (int j = 0; j < 2; ++j) {                                           \
                    int row = j * 16 + l15;                                             \
                    int sl = (kk * 4 + quad) ^ (l15 & 7);                               \
                    (FB)[kk * 2 + j] = *(const s16x8*)(&ca[w][BP][row * 64 + sl * 8]);  \
                }                                                                       \
        }

    // prologue: stage windows 0..3, then build A from fp32 z_e
    STAGE(0, 0); STAGE(1, 1); STAGE(2, 2); STAGE(3, 3);
    s16x8 af[4][8];
    #pragma unroll
    for (int i = 0; i < 4; ++i) {
        #pragma unroll
        for (int ks = 0; ks < 8; ++ks) {
            const float* p = z_e + (size_t)(t0 + wr * 64 + i * 16 + l15) * DIM + ks * 32 + quad * 8;
            float4 a = *(const float4*)p;
            float4 b = *(const float4*)(p + 4);
            s16x8 v;
            v[0] = (short)f2bf(a.x); v[1] = (short)f2bf(a.y);
            v[2] = (short)f2bf(a.z); v[3] = (short)f2bf(a.w);
            v[4] = (short)f2bf(b.x); v[5] = (short)f2bf(b.y);
            v[6] = (short)f2bf(b.z); v[7] = (short)f2bf(b.w);
            af[i][ks] = v;
        }
    }

    float best[4][4];
    int   bidx[4][4];
    #pragma unroll
    for (int i = 0; i < 4; ++i)
        #pragma unroll
        for (int r = 0; r < 4; ++r) { best[i][r] = FLT_MAX; bidx[i][r] = 0x7FFFFFFF; }

    s16x8 regB[2][4];
    __builtin_amdgcn_s_waitcnt(0x0F7C);   // vmcnt(12)
    READFRAGS(regB[0], 0, 0);

    for (int c = 0; c < 64; ++c) {
        f32x4 acc[4][2];
        #pragma unroll
        for (int i = 0; i < 4; ++i)
            #pragma unroll
            for (int j = 0; j < 2; ++j) acc[i][j] = (f32x4){0.f, 0.f, 0.f, 0.f};

        #pragma unroll
        for (int kw = 0; kw < 4; ++kw) {
            const int n = c * 4 + kw;
            __builtin_amdgcn_s_waitcnt(0xC07F);   // lgkmcnt(0): buf[n&3] recyclable
            STAGE((n + 4) & 255, n & 3);          // wrap keeps accounting uniform
            __builtin_amdgcn_s_waitcnt(0x0F78);   // vmcnt(8): st(n+1) drained
            READFRAGS(regB[(n + 1) & 1], (n + 1) & 255, (n + 1) & 3);
            // 16 MFMAs on window n (fragments read one iteration ago);
            // raise wave priority for the MFMA burst (AITER-style arbitration)
            const s16x8* cur = regB[n & 1];
            __builtin_amdgcn_s_setprio(1);
            #pragma unroll
            for (int kk = 0; kk < 2; ++kk)
                #pragma unroll
                for (int i = 0; i < 4; ++i)
                    #pragma unroll
                    for (int j = 0; j < 2; ++j)
                        acc[i][j] = __builtin_amdgcn_mfma_f32_16x16x32_bf16(af[i][kw * 2 + kk], cur[kk * 2 + j], acc[i][j], 0, 0, 0);
            __builtin_amdgcn_s_setprio(0);
        }

        // fold chunk c into running argmin: score = w2[col] - 2*dot
        #pragma unroll
        for (int j = 0; j < 2; ++j) {
            int col = c * 128 + wc * 32 + j * 16 + l15;
            float w2v = w2g[col];
            #pragma unroll
            for (int i = 0; i < 4; ++i)
                #pragma unroll
                for (int r = 0; r < 4; ++r) {
                    float s = fmaf(-2.0f, acc[i][j][r], w2v);
                    if (s < best[i][r]) { best[i][r] = s; bidx[i][r] = col; }  // ascending col: < keeps lowest
                }
        }
    }

    // cross-lane argmin over the 16 cols held per token row, then merge quarters
    #pragma unroll
    for (int i = 0; i < 4; ++i)
        #pragma unroll
        for (int r = 0; r < 4; ++r) {
            float b = best[i][r]; int ix = bidx[i][r];
            #pragma unroll
            for (int m = 1; m < 16; m <<= 1) {
                float ob = __shfl_xor(b, m);
                int   oi = __shfl_xor(ix, m);
                if (ob < b || (ob == b && oi < ix)) { b = ob; ix = oi; }
            }
            if (l15 == 0) {
                unsigned int fb = __float_as_uint(b);
                fb = (fb & 0x80000000u) ? ~fb : (fb | 0x80000000u);   // monotonic key
                unsigned long long key = ((unsigned long long)fb << 32) | (unsigned int)ix;
                atomicMin(&smin[wr * 64 + i * 16 + quad * 4 + r], key);
            }
        }
    __syncthreads();   // all waves' argmin merged before gather

    // fused gather + loss + flags/usage: wave w -> tokens [w*16, w*16+16)
    float lsum = 0.0f;
    for (int t = w * 16; t < w * 16 + 16; ++t) {
        int tok = t0 + t;
        int k = (int)(unsigned int)(smin[t] & 0xFFFFFFFFull);
        if (lane == 0) {
            int old = atomicExch(&flags[k], 1);       // device-scope
            if (old == 0) atomicAdd(&cnt[0], 1);      // count distinct codes
        }
        float4 cv = *(const float4*)(cb + (size_t)k * DIM + lane * 4);
        float4 zv = *(const float4*)(z_e + (size_t)tok * DIM + lane * 4);
        float dx = zv.x - cv.x, dy = zv.y - cv.y, dz = zv.z - cv.z, dw = zv.w - cv.w;
        lsum += dx * dx + dy * dy + dz * dz + dw * dw;
        *(float4*)(out + (size_t)tok * DIM + lane * 4) = cv;
    }
    #pragma unroll
    for (int m = 32; m >= 1; m >>= 1) lsum += __shfl_xor(lsum, m);
    if (lane == 0) wls[w] = lsum;
    __syncthreads();
    if (tid == 0) {
        float bsum = 0.0f;
        #pragma unroll
        for (int q = 0; q < 8; ++q) bsum += wls[q];
        // loss = codebook + 0.25*commitment = 1.25 * mean(diff^2)
        atomicAdd(out + LOSS_IDX, bsum * (1.25f / (float)LOSS_IDX));
        __threadfence();                              // my cnt[0] adds visible
        int done = atomicAdd(&cnt[1], 1);
        if (done == 255) {                            // last block finishes usage
            int used = atomicAdd(&cnt[0], 0);         // coherent read
            out[USAGE_IDX] = (float)used / (float)KC;
        }
    }
}

// ---------------------------------------------------------------------------
extern "C" void kernel_launch(void* const* d_in, const int* in_sizes, int n_in,
                              void* d_out, int out_size, void* d_ws, size_t ws_size,
                              hipStream_t stream) {
    (void)in_sizes; (void)n_in; (void)out_size; (void)ws_size;
    const float* z_e = (const float*)d_in[0];
    const float* cb  = (const float*)d_in[1];
    float* out = (float*)d_out;

    char* ws = (char*)d_ws;
    float* w2    = (float*)(ws + WS_W2);
    int*   flags = (int*)(ws + WS_FLAGS);
    int*   cnt   = (int*)(ws + WS_CNT);
    unsigned short* cbb = (unsigned short*)(ws + WS_CBF);

    vq_prep<<<KC / 8, 256, 0, stream>>>(cb, cbb, w2, flags, cnt, out);
    vq_main<<<T_TOTAL / 128, 512, 0, stream>>>(cbb, w2, z_e, cb, out, flags, cnt);
}

// Round 10
// 314.539 us; speedup vs baseline: 1.0827x; 1.0827x over previous
//
#include <hip/hip_runtime.h>
#include <float.h>

#define T_TOTAL 32768
#define KC      8192
#define DIM     256

#define LOSS_IDX  ((size_t)T_TOTAL * DIM)      // 8388608
#define USAGE_IDX (LOSS_IDX + 1)

typedef short s16x8 __attribute__((ext_vector_type(8)));
typedef float f32x4 __attribute__((ext_vector_type(4)));

// ws layout (bytes):
#define WS_W2    0                 // f32[8192]
#define WS_FLAGS 32768             // i32[8192]
#define WS_CNT   65536             // i32[2]: {used_count, blocks_done}
#define WS_CBP   65552             // u16[8192*256] packed fragment layout, 4 MB

__device__ __forceinline__ unsigned short f2bf(float f) {
    unsigned int u = __float_as_uint(f);
    u += 0x7FFFu + ((u >> 16) & 1u);   // RTNE
    return (unsigned short)(u >> 16);
}

// ---------------------------------------------------------------------------
// prep: cb -> fragment-packed bf16 + exact fp32 w2; flags zero; scalars zero.
// Packed layout (16B units): entry ((c*64 + wc*16 + j*8 + ks)*64 + lane) holds
// code = c*128+wc*32+j*16+(lane&15), k = ks*32+(lane>>4)*8 .. +7.
// A wave's fragment load is then ONE contiguous 1 KB global_load_dwordx4.
__global__ __launch_bounds__(256) void vq_prep(const float* __restrict__ cb,
                                               unsigned short* __restrict__ cbp,
                                               float* __restrict__ w2,
                                               int* __restrict__ flags,
                                               int* __restrict__ cnt,
                                               float* __restrict__ out) {
    const int blk = blockIdx.x, tid = threadIdx.x;
    const int code = blk * 8 + (tid >> 5);   // 32 threads per code row
    const int e8   = tid & 31;               // 8-elem chunk: k = e8*8
    const float* src = cb + (size_t)code * DIM + e8 * 8;
    float4 a = *(const float4*)src;
    float4 b = *(const float4*)(src + 4);
    uint4 o;
    o.x = (unsigned)f2bf(a.x) | ((unsigned)f2bf(a.y) << 16);
    o.y = (unsigned)f2bf(a.z) | ((unsigned)f2bf(a.w) << 16);
    o.z = (unsigned)f2bf(b.x) | ((unsigned)f2bf(b.y) << 16);
    o.w = (unsigned)f2bf(b.z) | ((unsigned)f2bf(b.w) << 16);
    // decompose code/k into packed coordinates
    const int l15 = code & 15;
    const int j   = (code >> 4) & 1;
    const int wc  = (code >> 5) & 3;
    const int c   = code >> 7;
    const int ks  = e8 >> 2;
    const int qd  = e8 & 3;
    size_t o16 = ((size_t)((c * 64 + wc * 16 + j * 8 + ks)) << 6) + qd * 16 + l15;
    *(uint4*)(cbp + o16 * 8) = o;
    // exact fp32 w2 (32-lane reduction within the row group)
    float s = a.x * a.x + a.y * a.y + a.z * a.z + a.w * a.w
            + b.x * b.x + b.y * b.y + b.z * b.z + b.w * b.w;
    #pragma unroll
    for (int m = 1; m <= 16; m <<= 1) s += __shfl_xor(s, m);
    if (e8 == 0) w2[code] = s;
    if (blk < 32) flags[blk * 256 + tid] = 0;
    if (blk == 0 && tid == 0) {
        out[LOSS_IDX] = 0.0f; out[USAGE_IDX] = 0.0f;
        cnt[0] = 0; cnt[1] = 0;
    }
}

// ---------------------------------------------------------------------------
// main: block = 128 tokens x all 8192 codes, grid 256, 8 waves.
// wave w: wr=w>>2 token half (64 tokens, A in regs/AGPRs), wc=w&3 code quarter.
// NO LDS in the K-loop: B fragments load straight from the fragment-packed
// codebook (1 contiguous KB per instruction) into a 4-deep register buffer.
// Compiler-tracked register deps give fine-grained vmcnt(N) pipelining:
// loads for step n+4 are issued right after the MFMAs of step n.
// (r9 lesson: no s_setprio — it fences the schedule and starves the co-wave.)
__global__ __launch_bounds__(512, 2) void vq_main(const unsigned short* __restrict__ cbp,
                                                  const float* __restrict__ w2g,
                                                  const float* __restrict__ z_e,
                                                  const float* __restrict__ cb,
                                                  float* __restrict__ out,
                                                  int* __restrict__ flags,
                                                  int* __restrict__ cnt) {
    __shared__ unsigned long long smin[128];
    __shared__ float wls[8];

    const int tid  = threadIdx.x;
    const int lane = tid & 63;
    const int w    = tid >> 6;        // 0..7
    const int wr   = w >> 2;          // token half
    const int wc   = w & 3;           // code quarter
    const int quad = lane >> 4;
    const int l15  = lane & 15;
    const int t0   = blockIdx.x * 128;

    if (tid < 128) smin[tid] = ~0ULL;
    __syncthreads();                  // smin published before any wave's epilogue

    // per-lane packed base for this wave's code quarter (s16x8 = 16B units)
    const s16x8* sbase = (const s16x8*)cbp + ((size_t)wc << 10) + lane;
    // fragment (c, j, ks) lives at sbase[(c*64 + j*8 + ks) << 6]

    // ---- prime pipeline: steps 0..3 of chunk 0 ----
    s16x8 bf[4][2];
    #pragma unroll
    for (int n = 0; n < 4; ++n) {
        bf[n][0] = sbase[(size_t)(n) << 6];
        bf[n][1] = sbase[(size_t)(8 + n) << 6];
    }

    // ---- A prologue: fp32 z_e -> bf16 fragments (long-latency overlap) ----
    s16x8 af[4][8];
    #pragma unroll
    for (int i = 0; i < 4; ++i) {
        #pragma unroll
        for (int ks = 0; ks < 8; ++ks) {
            const float* p = z_e + (size_t)(t0 + wr * 64 + i * 16 + l15) * DIM + ks * 32 + quad * 8;
            float4 a = *(const float4*)p;
            float4 b = *(const float4*)(p + 4);
            s16x8 v;
            v[0] = (short)f2bf(a.x); v[1] = (short)f2bf(a.y);
            v[2] = (short)f2bf(a.z); v[3] = (short)f2bf(a.w);
            v[4] = (short)f2bf(b.x); v[5] = (short)f2bf(b.y);
            v[6] = (short)f2bf(b.z); v[7] = (short)f2bf(b.w);
            af[i][ks] = v;
        }
    }

    float best[4][4];
    int   bidx[4][4];
    #pragma unroll
    for (int i = 0; i < 4; ++i)
        #pragma unroll
        for (int r = 0; r < 4; ++r) { best[i][r] = FLT_MAX; bidx[i][r] = 0x7FFFFFFF; }

    for (int c = 0; c < 64; ++c) {
        f32x4 acc[4][2];
        #pragma unroll
        for (int i = 0; i < 4; ++i)
            #pragma unroll
            for (int j = 0; j < 2; ++j) acc[i][j] = (f32x4){0.f, 0.f, 0.f, 0.f};

        #pragma unroll
        for (int ks = 0; ks < 8; ++ks) {
            const int sl = ks & 3;    // slot holding step n = c*8+ks (c*8 % 4 == 0)
            // 8 MFMAs on the current step's fragments
            #pragma unroll
            for (int i = 0; i < 4; ++i)
                #pragma unroll
                for (int j = 0; j < 2; ++j)
                    acc[i][j] = __builtin_amdgcn_mfma_f32_16x16x32_bf16(af[i][ks], bf[sl][j], acc[i][j], 0, 0, 0);
            // prefetch step n+4 into the just-freed slot (WAR keeps order)
            const int n4 = c * 8 + ks + 4;
            if (n4 < 512) {   // always true for ks<4; scalar branch on c for ks>=4
                const int cc = n4 >> 3, kss = n4 & 7;
                bf[sl][0] = sbase[(size_t)((cc * 64 + kss)) << 6];
                bf[sl][1] = sbase[(size_t)((cc * 64 + 8 + kss)) << 6];
            }
        }

        // fold chunk c into running argmin: score = w2[col] - 2*dot
        #pragma unroll
        for (int j = 0; j < 2; ++j) {
            int col = c * 128 + wc * 32 + j * 16 + l15;
            float w2v = w2g[col];
            #pragma unroll
            for (int i = 0; i < 4; ++i)
                #pragma unroll
                for (int r = 0; r < 4; ++r) {
                    float s = fmaf(-2.0f, acc[i][j][r], w2v);
                    if (s < best[i][r]) { best[i][r] = s; bidx[i][r] = col; }  // ascending col: < keeps lowest
                }
        }
    }

    // cross-lane argmin over the 16 cols held per token row, then merge quarters
    #pragma unroll
    for (int i = 0; i < 4; ++i)
        #pragma unroll
        for (int r = 0; r < 4; ++r) {
            float b = best[i][r]; int ix = bidx[i][r];
            #pragma unroll
            for (int m = 1; m < 16; m <<= 1) {
                float ob = __shfl_xor(b, m);
                int   oi = __shfl_xor(ix, m);
                if (ob < b || (ob == b && oi < ix)) { b = ob; ix = oi; }
            }
            if (l15 == 0) {
                unsigned int fb = __float_as_uint(b);
                fb = (fb & 0x80000000u) ? ~fb : (fb | 0x80000000u);   // monotonic key
                unsigned long long key = ((unsigned long long)fb << 32) | (unsigned int)ix;
                atomicMin(&smin[wr * 64 + i * 16 + quad * 4 + r], key);
            }
        }
    __syncthreads();   // all waves' argmin merged before gather

    // fused gather + loss + flags/usage: wave w -> tokens [w*16, w*16+16)
    float lsum = 0.0f;
    for (int t = w * 16; t < w * 16 + 16; ++t) {
        int tok = t0 + t;
        int k = (int)(unsigned int)(smin[t] & 0xFFFFFFFFull);
        if (lane == 0) {
            int old = atomicExch(&flags[k], 1);       // device-scope
            if (old == 0) atomicAdd(&cnt[0], 1);      // count distinct codes
        }
        float4 cv = *(const float4*)(cb + (size_t)k * DIM + lane * 4);
        float4 zv = *(const float4*)(z_e + (size_t)tok * DIM + lane * 4);
        float dx = zv.x - cv.x, dy = zv.y - cv.y, dz = zv.z - cv.z, dw = zv.w - cv.w;
        lsum += dx * dx + dy * dy + dz * dz + dw * dw;
        *(float4*)(out + (size_t)tok * DIM + lane * 4) = cv;
    }
    #pragma unroll
    for (int m = 32; m >= 1; m >>= 1) lsum += __shfl_xor(lsum, m);
    if (lane == 0) wls[w] = lsum;
    __syncthreads();
    if (tid == 0) {
        float bsum = 0.0f;
        #pragma unroll
        for (int q = 0; q < 8; ++q) bsum += wls[q];
        // loss = codebook + 0.25*commitment = 1.25 * mean(diff^2)
        atomicAdd(out + LOSS_IDX, bsum * (1.25f / (float)LOSS_IDX));
        __threadfence();                              // my cnt[0] adds visible
        int done = atomicAdd(&cnt[1], 1);
        if (done == 255) {                            // last block finishes usage
            int used = atomicAdd(&cnt[0], 0);         // coherent read
            out[USAGE_IDX] = (float)used / (float)KC;
        }
    }
}

// ---------------------------------------------------------------------------
extern "C" void kernel_launch(void* const* d_in, const int* in_sizes, int n_in,
                              void* d_out, int out_size, void* d_ws, size_t ws_size,
                              hipStream_t stream) {
    (void)in_sizes; (void)n_in; (void)out_size; (void)ws_size;
    const float* z_e = (const float*)d_in[0];
    const float* cb  = (const float*)d_in[1];
    float* out = (float*)d_out;

    char* ws = (char*)d_ws;
    float* w2    = (float*)(ws + WS_W2);
    int*   flags = (int*)(ws + WS_FLAGS);
    int*   cnt   = (int*)(ws + WS_CNT);
    unsigned short* cbp = (unsigned short*)(ws + WS_CBP);

    vq_prep<<<KC / 8, 256, 0, stream>>>(cb, cbp, w2, flags, cnt, out);
    vq_main<<<T_TOTAL / 128, 512, 0, stream>>>(cbp, w2, z_e, cb, out, flags, cnt);
}